// Round 12
// baseline (6887.755 us; speedup 1.0000x reference)
//
#include <hip/hip_runtime.h>
#include <hip/hip_fp16.h>

// Many2OneRNN: B=64, S=4096, I=256, H=256, O=128
// Fused heterogeneous kernel, chunked over time (T_C=1024, 4 chunks):
//   blocks 0..15   : recurrence, 4 CHAINS PER BLOCK (R12 interleave)
//   blocks 16..    : xp GEMM for chunk c+1 (128 t-rows/block, MFMA f16)
// R12: the per-step serial tax (post-barrier ds_read latency + dot->reduce->
//   tanh chain + 16-wave barrier spread, ~450 cyc — R9/R10/R11 showed MAC
//   issue count is NOT binding) is amortized 4x by interleaving 4 chains per
//   block: one barrier covers one step of all 4 chains; staggered reads hide
//   each chain's LDS latency under the previous chain's compute.
// rnn per thread per interval: 8 ds_read_b128, 4x(32 fdot2 + 5-DPP reduce +
//   tanh + predicated ds_write_b16), 1 raw barrier (lgkmcnt only).
// Phase 3 (out = sigmoid(Wya*a + Wya_b)) folded into the last rnn launch.

typedef _Float16 f16x8 __attribute__((ext_vector_type(8)));
typedef _Float16 f16x4 __attribute__((ext_vector_type(4)));
typedef _Float16 f16x2 __attribute__((ext_vector_type(2)));
typedef float    f32x4 __attribute__((ext_vector_type(4)));

#define FDOT2(a, b, c) __builtin_amdgcn_fdot2((a), (b), (c), false)

// row_ror:D within 16 lanes: dst lane i gets src lane (i-D)&15
template <int D>
__device__ __forceinline__ float rorf(float v) {
    return __builtin_bit_cast(float,
        __builtin_amdgcn_update_dpp(0, __builtin_bit_cast(int, v),
                                    0x120 + D, 0xF, 0xF, true));
}
// quad_perm rotate within 4 lanes: dst j gets src (j-D)&3
template <int D>
__device__ __forceinline__ float qrot(float v) {
    constexpr int ctrl = D == 1 ? 0x93 : (D == 2 ? 0x4E : 0x39);
    return __builtin_bit_cast(float,
        __builtin_amdgcn_update_dpp(0, __builtin_bit_cast(int, v),
                                    ctrl, 0xF, 0xF, true));
}

__global__ __launch_bounds__(1024)
__attribute__((amdgpu_waves_per_eu(4, 4)))
void k_fused(
    const float* __restrict__ x, const float* __restrict__ Ww,
    const float* __restrict__ Wb, const float* __restrict__ Waa,
    const float* __restrict__ Wab, const float* __restrict__ Wya,
    const float* __restrict__ Wyb, float* __restrict__ out,
    _Float16* __restrict__ xp0, _Float16* __restrict__ xp1,
    unsigned short* __restrict__ a_state,
    int c_rnn, int c_xp, int do_rnn, int do_xp, int is_last,
    int T_C, int logT)
{
    // LDS: xp path uses As (67.5 KB); rnn path uses aL (6 KB) + afin (4 KB).
    __shared__ __align__(16) _Float16 As[128 * 264];
    __shared__ __align__(16) _Float16 aL[2][4][16][24];  // [buf][chain][kchunk][16+8]
    __shared__ float afin[4][256];

    const int tid  = threadIdx.x;
    const int lane = tid & 63;

    if (blockIdx.x < 16) {
        // ================= RNN path: 4 chains per block =================
        if (!do_rnn) return;
        const _Float16* xp = (c_rnn & 1) ? xp1 : xp0;
        const int w     = tid >> 6;      // 0..15
        const int k     = lane & 15;     // K-slice [k*16, k*16+16)
        const int g     = lane >> 4;     // 0..3
        const int rbase = w * 16 + g * 4;
        const int myrow = rbase + (k & 3);
        const int bq    = blockIdx.x * 4;   // first chain of this block
        const bool wlane = (k & 12) == 0;

        // weights: slot i -> row rbase+((k+i)&3), K-contiguous f16x2 (32 VGPR)
        f16x2 wr[4][8];
#pragma unroll
        for (int i = 0; i < 4; ++i) {
            const float4* wp = (const float4*)(Waa + (size_t)(rbase + ((k + i) & 3)) * 256 + k * 16);
#pragma unroll
            for (int q = 0; q < 4; ++q) {
                float4 v = wp[q];
                f16x2 t0; t0[0] = (_Float16)v.x; t0[1] = (_Float16)v.y;
                f16x2 t1; t1[0] = (_Float16)v.z; t1[1] = (_Float16)v.w;
                wr[i][2 * q]     = t0;
                wr[i][2 * q + 1] = t1;
            }
        }
        const float bias = Wab[myrow];

        // init a buffers (4 chains x 256 rows), 1024 threads cover 1024 elems
        {
            const int ch = tid >> 8, r = tid & 255;
            unsigned short v = 0;
            if (c_rnn != 0) v = a_state[(bq + ch) * 256 + r];
            aL[0][ch][r >> 4][r & 15] = __builtin_bit_cast(_Float16, v);
        }
        __syncthreads();

        // xp streams: [b][h][t] layout, one b128 per 8 steps per chain
        const _Float16* xph[4];
#pragma unroll
        for (int ch = 0; ch < 4; ++ch)
            xph[ch] = xp + ((size_t)((bq + ch) * 256 + myrow)) * T_C;
        f16x8 xq[4], xn[4];
#pragma unroll
        for (int ch = 0; ch < 4; ++ch) xq[ch] = *(const f16x8*)(xph[ch]);

#define DO_READ(CUR, CH, R0, R1)                                             \
        {                                                                    \
            const _Float16* rp = &aL[(CUR)][(CH)][k][0];                     \
            R0 = *(const uint4*)(rp);                                        \
            R1 = *(const uint4*)(rp + 8);                                    \
        }

#define DO_COMP(CUR, CH, R0, R1, J, FIN)                                     \
        {                                                                    \
            f16x2 a2[8];                                                     \
            a2[0] = __builtin_bit_cast(f16x2, R0.x);                         \
            a2[1] = __builtin_bit_cast(f16x2, R0.y);                         \
            a2[2] = __builtin_bit_cast(f16x2, R0.z);                         \
            a2[3] = __builtin_bit_cast(f16x2, R0.w);                         \
            a2[4] = __builtin_bit_cast(f16x2, R1.x);                         \
            a2[5] = __builtin_bit_cast(f16x2, R1.y);                         \
            a2[6] = __builtin_bit_cast(f16x2, R1.z);                         \
            a2[7] = __builtin_bit_cast(f16x2, R1.w);                         \
            float s0 = 0.f, s1 = 0.f, s2 = 0.f, s3 = 0.f;                    \
            _Pragma("unroll")                                                \
            for (int q = 0; q < 8; ++q) {                                    \
                s0 = FDOT2(wr[0][q], a2[q], s0);                             \
                s1 = FDOT2(wr[1][q], a2[q], s1);                             \
                s2 = FDOT2(wr[2][q], a2[q], s2);                             \
                s3 = FDOT2(wr[3][q], a2[q], s3);                             \
            }                                                                \
            float t = s0 + qrot<1>(s1);                                      \
            t += qrot<2>(s2);                                                \
            t += qrot<3>(s3);                                                \
            float u   = t + rorf<4>(t);                                      \
            float acc = u + rorf<8>(u);                                      \
            float z  = bias + (float)xq[(CH)][(J)] + acc;                    \
            float e2 = __expf(2.f * z);                                      \
            float a  = fmaf(-2.f, __builtin_amdgcn_rcpf(e2 + 1.f), 1.f);     \
            _Float16 ah = (_Float16)a;                                       \
            if (wlane) aL[(CUR) ^ 1][(CH)][w][g * 4 + k] = ah;               \
            if (FIN) {                                                       \
                afin[(CH)][myrow] = a;                                       \
                a_state[(bq + (CH)) * 256 + myrow] =                         \
                    __builtin_bit_cast(unsigned short, ah);                  \
            }                                                                \
        }

#define INTERVAL(CUR, J, FIN)                                                \
        {                                                                    \
            uint4 ra0, ra1, rb0, rb1, rc0, rc1, rd0, rd1;                    \
            DO_READ(CUR, 0, ra0, ra1)                                        \
            DO_READ(CUR, 1, rb0, rb1)                                        \
            DO_COMP(CUR, 0, ra0, ra1, J, FIN)                                \
            DO_READ(CUR, 2, rc0, rc1)                                        \
            DO_COMP(CUR, 1, rb0, rb1, J, FIN)                                \
            DO_READ(CUR, 3, rd0, rd1)                                        \
            DO_COMP(CUR, 2, rc0, rc1, J, FIN)                                \
            DO_COMP(CUR, 3, rd0, rd1, J, FIN)                                \
            asm volatile("s_waitcnt lgkmcnt(0)" ::: "memory");               \
            __builtin_amdgcn_s_barrier();                                    \
            asm volatile("" ::: "memory");                                   \
        }

        for (int tb = 0; tb + 8 < T_C; tb += 8) {
#pragma unroll
            for (int ch = 0; ch < 4; ++ch)
                xn[ch] = *(const f16x8*)(xph[ch] + tb + 8);
            INTERVAL(0, 0, false) INTERVAL(1, 1, false)
            INTERVAL(0, 2, false) INTERVAL(1, 3, false)
            INTERVAL(0, 4, false) INTERVAL(1, 5, false)
            INTERVAL(0, 6, false) INTERVAL(1, 7, false)
#pragma unroll
            for (int ch = 0; ch < 4; ++ch) xq[ch] = xn[ch];
        }
        // peeled tail: finalize on j==7
        INTERVAL(0, 0, false) INTERVAL(1, 1, false)
        INTERVAL(0, 2, false) INTERVAL(1, 3, false)
        INTERVAL(0, 4, false) INTERVAL(1, 5, false)
        INTERVAL(0, 6, false) INTERVAL(1, 7, true)
#undef INTERVAL
#undef DO_COMP
#undef DO_READ

        // --- Phase 3: out = sigmoid(Wya * a_last + Wyb), last chunk only.
        // afin visible: written before the last interval's lgkmcnt+barrier.
        if (is_last) {
            const int ch = tid >> 8;          // 0..3
            if ((tid & 128) == 0) {
                const int o = tid & 127;
                const float4* wp = (const float4*)(Wya + (size_t)o * 256);
                const float4* ap = (const float4*)(&afin[ch][0]);
                float s = Wyb[o];
#pragma unroll 8
                for (int i = 0; i < 64; ++i) {
                    float4 wv4 = wp[i];
                    float4 a4  = ap[i];
                    s += wv4.x * a4.x + wv4.y * a4.y + wv4.z * a4.z + wv4.w * a4.w;
                }
                out[(bq + ch) * 128 + o] = __builtin_amdgcn_rcpf(1.f + __expf(-s));
            }
        }
    } else {
        // ================= XP path (chunk c_xp, 128 t-rows/block) =========
        if (!do_xp) return;
        _Float16* xp = (c_xp & 1) ? xp1 : xp0;
        const int bxp = blockIdx.x - 16;
        const int wv  = tid >> 6;    // 0..15
        const int l15 = lane & 15;
        const int lk  = lane >> 4;   // 0..3
        const int n0  = wv * 16;

        // B fragments: Wax_w rows n0+l15 (16 cols per wave), K-contiguous
        f16x8 bfr[8];
        {
            const float* wrow = Ww + (size_t)(n0 + l15) * 256;
#pragma unroll
            for (int kt = 0; kt < 8; ++kt) {
                const float4* wp = (const float4*)(wrow + kt * 32 + lk * 8);
                float4 v0 = wp[0], v1 = wp[1];
                f16x8 f;
                f[0] = (_Float16)v0.x; f[1] = (_Float16)v0.y;
                f[2] = (_Float16)v0.z; f[3] = (_Float16)v0.w;
                f[4] = (_Float16)v1.x; f[5] = (_Float16)v1.y;
                f[6] = (_Float16)v1.z; f[7] = (_Float16)v1.w;
                bfr[kt] = f;
            }
        }
        const float bias = Wb[n0 + l15];

        // stage A tile (128 rows x 256 K) f32 -> f16 LDS
        {
            const int arow = tid >> 3;           // 0..127
            const int acol = (tid & 7) * 32;     // 0..224
            const int r    = bxp * 128 + arow;
            const int bb   = r >> logT;
            const int tl   = r & (T_C - 1);
            const float4* s4 = (const float4*)(x + ((size_t)(bb * 4096 + c_xp * T_C + tl) << 8) + acol);
            _Float16* d = As + arow * 264 + acol;
#pragma unroll
            for (int q = 0; q < 4; ++q) {
                float4 v0 = s4[2 * q], v1 = s4[2 * q + 1];
                f16x8 p;
                p[0] = (_Float16)v0.x; p[1] = (_Float16)v0.y;
                p[2] = (_Float16)v0.z; p[3] = (_Float16)v0.w;
                p[4] = (_Float16)v1.x; p[5] = (_Float16)v1.y;
                p[6] = (_Float16)v1.z; p[7] = (_Float16)v1.w;
                *(f16x8*)(d + q * 8) = p;
            }
        }
        __syncthreads();

        f32x4 acc[8] = {};
#pragma unroll
        for (int kt = 0; kt < 8; ++kt) {
#pragma unroll
            for (int mt = 0; mt < 8; ++mt) {
                f16x8 af = *(const f16x8*)(As + (mt * 16 + l15) * 264 + kt * 32 + lk * 8);
                acc[mt] = __builtin_amdgcn_mfma_f32_16x16x32_f16(af, bfr[kt], acc[mt], 0, 0, 0);
            }
        }

        // store xp3[b][h][t]: 4 t-contiguous halves per 8B store
        const int base = bxp * 128;
#pragma unroll
        for (int mt = 0; mt < 8; ++mt) {
            const int rr  = base + mt * 16 + lk * 4;
            const int bb2 = rr >> logT;
            const int tt  = rr & (T_C - 1);
            f16x4 pk;
#pragma unroll
            for (int r2 = 0; r2 < 4; ++r2) pk[r2] = (_Float16)(acc[mt][r2] + bias);
            *(f16x4*)(xp + ((size_t)(bb2 * 256 + n0 + l15)) * T_C + tt) = pk;
        }
    }
}

// ---------------------------------------------------------------------------
extern "C" void kernel_launch(void* const* d_in, const int* in_sizes, int n_in,
                              void* d_out, int out_size, void* d_ws, size_t ws_size,
                              hipStream_t stream)
{
    (void)in_sizes; (void)n_in; (void)out_size;
    const float* x    = (const float*)d_in[0];
    const float* Waxw = (const float*)d_in[1];
    const float* Waxb = (const float*)d_in[2];
    const float* Waaw = (const float*)d_in[3];
    const float* Waab = (const float*)d_in[4];
    const float* Wyaw = (const float*)d_in[5];
    const float* Wyab = (const float*)d_in[6];
    float* out = (float*)d_out;

    // chunk size: T_C=1024 (4 chunks) for xp/rnn overlap; shrink to fit ws
    // (needs 2 xp chunk buffers + 32KB state).
    int T_C = 1024, logT = 10;
    while (T_C > 128 && (size_t)2 * 64 * T_C * 256 * 2 + 32768 > ws_size) { T_C >>= 1; --logT; }

    _Float16* xp0 = (_Float16*)d_ws;
    _Float16* xp1 = xp0 + (size_t)64 * T_C * 256;
    unsigned short* a_state = (unsigned short*)(xp1 + (size_t)64 * T_C * 256);

    const int nc  = 4096 / T_C;
    const int nxp = 64 * T_C / 128;   // xp blocks per chunk
    for (int i = 0; i <= nc; ++i) {
        // launch i: rnn on chunk i-1 (if any) overlapped with xp on chunk i
        k_fused<<<dim3(16 + nxp), dim3(1024), 0, stream>>>(
            x, Waxw, Waxb, Waaw, Waab, Wyaw, Wyab, out, xp0, xp1, a_state,
            i - 1, i, i >= 1 ? 1 : 0, i < nc ? 1 : 0, i == nc ? 1 : 0,
            T_C, logT);
    }
}

// Round 13
// 2030.214 us; speedup vs baseline: 3.3926x; 3.3926x over previous
//
#include <hip/hip_runtime.h>
#include <hip/hip_fp16.h>

// Many2OneRNN: B=64, S=4096, I=256, H=256, O=128
// Fused heterogeneous kernel, chunked over time (T_C=1024, 4 chunks):
//   blocks 0..63   : recurrence for chunk c   (1 block/chain, 1024 thr)
//   blocks 64..    : xp GEMM for chunk c+1    (128 t-rows/block, MFMA f16)
// xp double-buffered in d_ws so launch i overlaps rnn(i-1) with xp(i).
// R13 = R9 structure (best measured: 1958 us) + inline-asm v_dot2_f32_f16
//   with "v" register-class constraints: forces the 32-dword weight array
//   into arch VGPRs at every use, eliminating the suspected accvgpr_read
//   traffic (VGPR_Count stuck at ~52 across R4-R11 while >=60 values are
//   live -> compiler AGPR-parks weights; unified file makes that pure
//   overhead).  Non-volatile asm keeps the 4 dot chains schedulable.
// rnn per thread/step: 2 ds_read_b128 (broadcast), 32 asm dot2, 5-DPP
//   quad_perm+row_ror rotate-reduce, 5-op tanh, predicated ds_write_b16,
//   1 raw barrier (lgkmcnt only — xp prefetch stays in flight).
// Phase 3 (out = sigmoid(Wya*a + Wya_b)) folded into the last rnn launch.

typedef _Float16 f16x8 __attribute__((ext_vector_type(8)));
typedef _Float16 f16x4 __attribute__((ext_vector_type(4)));
typedef _Float16 f16x2 __attribute__((ext_vector_type(2)));
typedef float    f32x4 __attribute__((ext_vector_type(4)));

// acc = dot2(w, a) + acc, forced into arch VGPRs ("v" class).  Non-volatile
// pure-dataflow asm: compiler may schedule/interleave the 4 chains.
#define FDOT2A(w, a, acc)                                                    \
    asm("v_dot2_f32_f16 %0, %1, %2, %0"                                     \
        : "+v"(acc) : "v"(w), "v"(a))

// row_ror:D within 16 lanes: dst lane i gets src lane (i-D)&15
template <int D>
__device__ __forceinline__ float rorf(float v) {
    return __builtin_bit_cast(float,
        __builtin_amdgcn_update_dpp(0, __builtin_bit_cast(int, v),
                                    0x120 + D, 0xF, 0xF, true));
}
// quad_perm rotate within 4 lanes: dst j gets src (j-D)&3
template <int D>
__device__ __forceinline__ float qrot(float v) {
    constexpr int ctrl = D == 1 ? 0x93 : (D == 2 ? 0x4E : 0x39);
    return __builtin_bit_cast(float,
        __builtin_amdgcn_update_dpp(0, __builtin_bit_cast(int, v),
                                    ctrl, 0xF, 0xF, true));
}

__global__ __launch_bounds__(1024)
__attribute__((amdgpu_waves_per_eu(4, 4)))
void k_fused(
    const float* __restrict__ x, const float* __restrict__ Ww,
    const float* __restrict__ Wb, const float* __restrict__ Waa,
    const float* __restrict__ Wab, const float* __restrict__ Wya,
    const float* __restrict__ Wyb, float* __restrict__ out,
    _Float16* __restrict__ xp0, _Float16* __restrict__ xp1,
    unsigned short* __restrict__ a_state,
    int c_rnn, int c_xp, int do_rnn, int do_xp, int is_last,
    int T_C, int logT)
{
    // LDS: xp path uses As (67.5 KB); rnn path uses aL/afin (2.5 KB).
    __shared__ __align__(16) _Float16 As[128 * 264];
    __shared__ __align__(16) _Float16 aL[2][16][24];
    __shared__ float afin[256];

    const int tid  = threadIdx.x;
    const int lane = tid & 63;

    if (blockIdx.x < 64) {
        // ================= RNN path =================
        if (!do_rnn) return;
        const _Float16* xp = (c_rnn & 1) ? xp1 : xp0;
        const int w     = tid >> 6;      // 0..15
        const int k     = lane & 15;     // K-slice [k*16, k*16+16)
        const int g     = lane >> 4;     // 0..3
        const int rbase = w * 16 + g * 4;
        const int myrow = rbase + (k & 3);
        const int b     = blockIdx.x;
        const bool wlane = (k & 12) == 0;

        // weights: slot i -> row rbase+((k+i)&3), K-contiguous f16x2
        f16x2 wr[4][8];
#pragma unroll
        for (int i = 0; i < 4; ++i) {
            const float4* wp = (const float4*)(Waa + (size_t)(rbase + ((k + i) & 3)) * 256 + k * 16);
#pragma unroll
            for (int q = 0; q < 4; ++q) {
                float4 v = wp[q];
                f16x2 t0; t0[0] = (_Float16)v.x; t0[1] = (_Float16)v.y;
                f16x2 t1; t1[0] = (_Float16)v.z; t1[1] = (_Float16)v.w;
                wr[i][2 * q]     = t0;
                wr[i][2 * q + 1] = t1;
            }
        }
        const float bias = Wab[myrow];

        if (tid < 256) {
            unsigned short v = 0;
            if (c_rnn != 0) v = a_state[b * 256 + tid];
            aL[0][tid >> 4][tid & 15] = __builtin_bit_cast(_Float16, v);
        }
        __syncthreads();

        const _Float16* xph = xp + ((size_t)(b * 256 + myrow)) * T_C;
        f16x8 xq = *(const f16x8*)(xph);
        float bx[8];
#pragma unroll
        for (int j = 0; j < 8; ++j) bx[j] = bias + (float)xq[j];

        const _Float16* rp0 = &aL[0][k][0];
        const _Float16* rp1 = &aL[1][k][0];
        _Float16* wq0 = &aL[1][w][g * 4 + k];  // wlane only (k<4)
        _Float16* wq1 = &aL[0][w][g * 4 + k];

#define RNN_STEP(J, FIN)                                                     \
    {                                                                        \
        const _Float16* rp = ((J) & 1) ? rp1 : rp0;                          \
        uint4 r0 = *(const uint4*)(rp);                                      \
        uint4 r1 = *(const uint4*)(rp + 8);                                  \
        f16x2 a2[8];                                                         \
        a2[0] = __builtin_bit_cast(f16x2, r0.x);                             \
        a2[1] = __builtin_bit_cast(f16x2, r0.y);                             \
        a2[2] = __builtin_bit_cast(f16x2, r0.z);                             \
        a2[3] = __builtin_bit_cast(f16x2, r0.w);                             \
        a2[4] = __builtin_bit_cast(f16x2, r1.x);                             \
        a2[5] = __builtin_bit_cast(f16x2, r1.y);                             \
        a2[6] = __builtin_bit_cast(f16x2, r1.z);                             \
        a2[7] = __builtin_bit_cast(f16x2, r1.w);                             \
        float s0 = 0.f, s1 = 0.f, s2 = 0.f, s3 = 0.f;                        \
        _Pragma("unroll")                                                    \
        for (int q = 0; q < 8; ++q) {                                        \
            FDOT2A(wr[0][q], a2[q], s0);                                     \
            FDOT2A(wr[1][q], a2[q], s1);                                     \
            FDOT2A(wr[2][q], a2[q], s2);                                     \
            FDOT2A(wr[3][q], a2[q], s3);                                     \
        }                                                                    \
        /* 5-DPP reduce: quad rotate-reduce then fold the 4 quads */         \
        float t = s0 + qrot<1>(s1);                                          \
        t += qrot<2>(s2);                                                    \
        t += qrot<3>(s3);                                                    \
        float u   = t + rorf<4>(t);                                          \
        float acc = u + rorf<8>(u);                                          \
        float z  = bx[(J)] + acc;                                            \
        float e2 = __expf(2.f * z);                                          \
        float a  = fmaf(-2.f, __builtin_amdgcn_rcpf(e2 + 1.f), 1.f);         \
        _Float16 ah = (_Float16)a;                                           \
        if (wlane) *(((J) & 1) ? wq1 : wq0) = ah;                            \
        if (FIN) {                                                           \
            afin[myrow] = a;                                                 \
            a_state[b * 256 + myrow] = __builtin_bit_cast(unsigned short, ah);\
        }                                                                    \
        asm volatile("s_waitcnt lgkmcnt(0)" ::: "memory");                   \
        __builtin_amdgcn_s_barrier();                                        \
        asm volatile("" ::: "memory");                                       \
    }

        for (int tb = 0; tb + 8 < T_C; tb += 8) {
            f16x8 xn = *(const f16x8*)(xph + tb + 8);
            RNN_STEP(0, false) RNN_STEP(1, false) RNN_STEP(2, false) RNN_STEP(3, false)
            RNN_STEP(4, false) RNN_STEP(5, false) RNN_STEP(6, false) RNN_STEP(7, false)
#pragma unroll
            for (int j = 0; j < 8; ++j) bx[j] = bias + (float)xn[j];
        }
        RNN_STEP(0, false) RNN_STEP(1, false) RNN_STEP(2, false) RNN_STEP(3, false)
        RNN_STEP(4, false) RNN_STEP(5, false) RNN_STEP(6, false) RNN_STEP(7, true)
#undef RNN_STEP

        if (is_last) {
            const int o  = tid >> 3;   // 0..127
            const int k8 = tid & 7;
            const float4* wp = (const float4*)(Wya + (size_t)o * 256 + k8 * 32);
            const float4* ap = (const float4*)(afin + k8 * 32);
            float s = 0.f;
#pragma unroll
            for (int i = 0; i < 8; ++i) {
                float4 wv4 = wp[i];
                float4 a4  = ap[i];
                s += wv4.x * a4.x + wv4.y * a4.y + wv4.z * a4.z + wv4.w * a4.w;
            }
            s += __shfl_xor(s, 1);
            s += __shfl_xor(s, 2);
            s += __shfl_xor(s, 4);
            if (k8 == 0)
                out[b * 128 + o] = __builtin_amdgcn_rcpf(1.f + __expf(-(s + Wyb[o])));
        }
    } else {
        // ================= XP path (chunk c_xp, 128 t-rows/block) =========
        if (!do_xp) return;
        _Float16* xp = (c_xp & 1) ? xp1 : xp0;
        const int bxp = blockIdx.x - 64;
        const int wv  = tid >> 6;    // 0..15
        const int l15 = lane & 15;
        const int lk  = lane >> 4;   // 0..3
        const int n0  = wv * 16;

        // B fragments: Wax_w rows n0+l15 (16 cols per wave), K-contiguous
        f16x8 bfr[8];
        {
            const float* wrow = Ww + (size_t)(n0 + l15) * 256;
#pragma unroll
            for (int kt = 0; kt < 8; ++kt) {
                const float4* wp = (const float4*)(wrow + kt * 32 + lk * 8);
                float4 v0 = wp[0], v1 = wp[1];
                f16x8 f;
                f[0] = (_Float16)v0.x; f[1] = (_Float16)v0.y;
                f[2] = (_Float16)v0.z; f[3] = (_Float16)v0.w;
                f[4] = (_Float16)v1.x; f[5] = (_Float16)v1.y;
                f[6] = (_Float16)v1.z; f[7] = (_Float16)v1.w;
                bfr[kt] = f;
            }
        }
        const float bias = Wb[n0 + l15];

        // stage A tile (128 rows x 256 K) f32 -> f16 LDS
        {
            const int arow = tid >> 3;           // 0..127
            const int acol = (tid & 7) * 32;     // 0..224
            const int r    = bxp * 128 + arow;
            const int bb   = r >> logT;
            const int tl   = r & (T_C - 1);
            const float4* s4 = (const float4*)(x + ((size_t)(bb * 4096 + c_xp * T_C + tl) << 8) + acol);
            _Float16* d = As + arow * 264 + acol;
#pragma unroll
            for (int q = 0; q < 4; ++q) {
                float4 v0 = s4[2 * q], v1 = s4[2 * q + 1];
                f16x8 p;
                p[0] = (_Float16)v0.x; p[1] = (_Float16)v0.y;
                p[2] = (_Float16)v0.z; p[3] = (_Float16)v0.w;
                p[4] = (_Float16)v1.x; p[5] = (_Float16)v1.y;
                p[6] = (_Float16)v1.z; p[7] = (_Float16)v1.w;
                *(f16x8*)(d + q * 8) = p;
            }
        }
        __syncthreads();

        f32x4 acc[8] = {};
#pragma unroll
        for (int kt = 0; kt < 8; ++kt) {
#pragma unroll
            for (int mt = 0; mt < 8; ++mt) {
                f16x8 af = *(const f16x8*)(As + (mt * 16 + l15) * 264 + kt * 32 + lk * 8);
                acc[mt] = __builtin_amdgcn_mfma_f32_16x16x32_f16(af, bfr[kt], acc[mt], 0, 0, 0);
            }
        }

        // store xp3[b][h][t]: 4 t-contiguous halves per 8B store
        const int base = bxp * 128;
#pragma unroll
        for (int mt = 0; mt < 8; ++mt) {
            const int rr  = base + mt * 16 + lk * 4;
            const int bb2 = rr >> logT;
            const int tt  = rr & (T_C - 1);
            f16x4 pk;
#pragma unroll
            for (int r2 = 0; r2 < 4; ++r2) pk[r2] = (_Float16)(acc[mt][r2] + bias);
            *(f16x4*)(xp + ((size_t)(bb2 * 256 + n0 + l15)) * T_C + tt) = pk;
        }
    }
}

// ---------------------------------------------------------------------------
extern "C" void kernel_launch(void* const* d_in, const int* in_sizes, int n_in,
                              void* d_out, int out_size, void* d_ws, size_t ws_size,
                              hipStream_t stream)
{
    (void)in_sizes; (void)n_in; (void)out_size;
    const float* x    = (const float*)d_in[0];
    const float* Waxw = (const float*)d_in[1];
    const float* Waxb = (const float*)d_in[2];
    const float* Waaw = (const float*)d_in[3];
    const float* Waab = (const float*)d_in[4];
    const float* Wyaw = (const float*)d_in[5];
    const float* Wyab = (const float*)d_in[6];
    float* out = (float*)d_out;

    // chunk size: T_C=1024 (4 chunks) for xp/rnn overlap; shrink to fit ws
    // (needs 2 xp chunk buffers + 32KB state).
    int T_C = 1024, logT = 10;
    while (T_C > 128 && (size_t)2 * 64 * T_C * 256 * 2 + 32768 > ws_size) { T_C >>= 1; --logT; }

    _Float16* xp0 = (_Float16*)d_ws;
    _Float16* xp1 = xp0 + (size_t)64 * T_C * 256;
    unsigned short* a_state = (unsigned short*)(xp1 + (size_t)64 * T_C * 256);

    const int nc  = 4096 / T_C;
    const int nxp = 64 * T_C / 128;   // xp blocks per chunk
    for (int i = 0; i <= nc; ++i) {
        // launch i: rnn on chunk i-1 (if any) overlapped with xp on chunk i
        k_fused<<<dim3(64 + nxp), dim3(1024), 0, stream>>>(
            x, Waxw, Waxb, Waaw, Waab, Wyaw, Wyab, out, xp0, xp1, a_state,
            i - 1, i, i >= 1 ? 1 : 0, i < nc ? 1 : 0, i == nc ? 1 : 0,
            T_C, logT);
    }
}

// Round 14
// 1916.513 us; speedup vs baseline: 3.5939x; 1.0593x over previous
//
#include <hip/hip_runtime.h>
#include <hip/hip_fp16.h>

// Many2OneRNN: B=64, S=4096, I=256, H=256, O=128
// Fused heterogeneous kernel, chunked over time (T_C=1024, 4 chunks):
//   blocks 0..63   : recurrence for chunk c (1 block/chain, 512 thr, 8 waves)
//   blocks 64..    : xp GEMM for chunk c+1  (64 t-rows/block, MFMA f16)
// xp double-buffered in d_ws so launch i overlaps rnn(i-1) with xp(i).
// R14: 512 threads / 8 rows per thread (row redundancy 2 instead of 4).
//   MAC issue per SIMD is invariant (512 cyc: dot2 is half-rate, confirmed
//   R9/R10/R11/R13), but glue is per-thread: 2 waves x ~55 glue beats
//   4 waves x ~45.  R2's failure at this shape was weight demotion +
//   per-step scalar xp loads — both fixed here (waves_per_eu budget,
//   [b][h][t] oct loads).
// rnn per thread/step: 2 ds_read_b128 (broadcast), 64 fdot2, 15-DPP
//   period-8 rotate-reduce, 5-op tanh, predicated ds_write_b16 (k<8),
//   1 raw barrier (lgkmcnt only — xp prefetch stays in flight).
// Phase 3 (out = sigmoid(Wya*a + Wya_b)) folded into the last rnn launch.

typedef _Float16 f16x8 __attribute__((ext_vector_type(8)));
typedef _Float16 f16x4 __attribute__((ext_vector_type(4)));
typedef _Float16 f16x2 __attribute__((ext_vector_type(2)));
typedef float    f32x4 __attribute__((ext_vector_type(4)));

#define FDOT2(a, b, c) __builtin_amdgcn_fdot2((a), (b), (c), false)

// row_ror:D within 16 lanes: dst lane i gets src lane (i-D)&15
template <int D>
__device__ __forceinline__ float rorf(float v) {
    return __builtin_bit_cast(float,
        __builtin_amdgcn_update_dpp(0, __builtin_bit_cast(int, v),
                                    0x120 + D, 0xF, 0xF, true));
}

__global__ __launch_bounds__(512)
__attribute__((amdgpu_waves_per_eu(2, 2)))
void k_fused(
    const float* __restrict__ x, const float* __restrict__ Ww,
    const float* __restrict__ Wb, const float* __restrict__ Waa,
    const float* __restrict__ Wab, const float* __restrict__ Wya,
    const float* __restrict__ Wyb, float* __restrict__ out,
    _Float16* __restrict__ xp0, _Float16* __restrict__ xp1,
    unsigned short* __restrict__ a_state,
    int c_rnn, int c_xp, int do_rnn, int do_xp, int is_last,
    int T_C, int logT)
{
    // LDS: xp path uses As (33.8 KB); rnn path uses aL/afin (2.5 KB).
    __shared__ __align__(16) _Float16 As[64 * 264];
    __shared__ __align__(16) _Float16 aL[2][16][24];
    __shared__ float afin[256];

    const int tid  = threadIdx.x;
    const int lane = tid & 63;

    if (blockIdx.x < 64) {
        // ================= RNN path: 8 rows/thread =================
        if (!do_rnn) return;
        const _Float16* xp = (c_rnn & 1) ? xp1 : xp0;
        const int w     = tid >> 6;      // 0..7
        const int k     = lane & 15;     // K-slice [k*16, k*16+16)
        const int g     = lane >> 4;     // 0..3
        const int rbase = w * 32 + g * 8;
        const int myrow = rbase + (k & 7);
        const int b     = blockIdx.x;
        const bool wlane = (k & 8) == 0;   // 8 writer lanes cover the 8 rows

        // weights: slot i -> row rbase+((k+i)&7), K-contiguous f16x2 (64 VGPR)
        f16x2 wr[8][8];
#pragma unroll
        for (int i = 0; i < 8; ++i) {
            const float4* wp = (const float4*)(Waa + (size_t)(rbase + ((k + i) & 7)) * 256 + k * 16);
#pragma unroll
            for (int q = 0; q < 4; ++q) {
                float4 v = wp[q];
                f16x2 t0; t0[0] = (_Float16)v.x; t0[1] = (_Float16)v.y;
                f16x2 t1; t1[0] = (_Float16)v.z; t1[1] = (_Float16)v.w;
                wr[i][2 * q]     = t0;
                wr[i][2 * q + 1] = t1;
            }
        }
        const float bias = Wab[myrow];

        if (tid < 256) {
            unsigned short v = 0;
            if (c_rnn != 0) v = a_state[b * 256 + tid];
            aL[0][tid >> 4][tid & 15] = __builtin_bit_cast(_Float16, v);
        }
        __syncthreads();

        const _Float16* xph = xp + ((size_t)(b * 256 + myrow)) * T_C;
        f16x8 xq = *(const f16x8*)(xph);
        float bx[8];
#pragma unroll
        for (int j = 0; j < 8; ++j) bx[j] = bias + (float)xq[j];

        const _Float16* rp0 = &aL[0][k][0];
        const _Float16* rp1 = &aL[1][k][0];
        _Float16* wq0 = &aL[1][myrow >> 4][myrow & 15];  // wlane only
        _Float16* wq1 = &aL[0][myrow >> 4][myrow & 15];

#define RNN_STEP(J, FIN)                                                     \
    {                                                                        \
        const _Float16* rp = ((J) & 1) ? rp1 : rp0;                          \
        uint4 r0 = *(const uint4*)(rp);                                      \
        uint4 r1 = *(const uint4*)(rp + 8);                                  \
        f16x2 a2[8];                                                         \
        a2[0] = __builtin_bit_cast(f16x2, r0.x);                             \
        a2[1] = __builtin_bit_cast(f16x2, r0.y);                             \
        a2[2] = __builtin_bit_cast(f16x2, r0.z);                             \
        a2[3] = __builtin_bit_cast(f16x2, r0.w);                             \
        a2[4] = __builtin_bit_cast(f16x2, r1.x);                             \
        a2[5] = __builtin_bit_cast(f16x2, r1.y);                             \
        a2[6] = __builtin_bit_cast(f16x2, r1.z);                             \
        a2[7] = __builtin_bit_cast(f16x2, r1.w);                             \
        float s0 = 0.f, s1 = 0.f, s2 = 0.f, s3 = 0.f;                        \
        float s4 = 0.f, s5 = 0.f, s6 = 0.f, s7 = 0.f;                        \
        _Pragma("unroll")                                                    \
        for (int q = 0; q < 8; ++q) {                                        \
            s0 = FDOT2(wr[0][q], a2[q], s0);                                 \
            s1 = FDOT2(wr[1][q], a2[q], s1);                                 \
            s2 = FDOT2(wr[2][q], a2[q], s2);                                 \
            s3 = FDOT2(wr[3][q], a2[q], s3);                                 \
            s4 = FDOT2(wr[4][q], a2[q], s4);                                 \
            s5 = FDOT2(wr[5][q], a2[q], s5);                                 \
            s6 = FDOT2(wr[6][q], a2[q], s6);                                 \
            s7 = FDOT2(wr[7][q], a2[q], s7);                                 \
        }                                                                    \
        /* period-8 rotate-reduce over 16 K-lanes:                           \
           total(row k&7) = sum_c ror_c( p_c + ror4(p_{c+4}) ),              \
           p_i = s_i + ror8(s_i) */                                          \
        float p0 = s0 + rorf<8>(s0);                                         \
        float p1 = s1 + rorf<8>(s1);                                         \
        float p2 = s2 + rorf<8>(s2);                                         \
        float p3 = s3 + rorf<8>(s3);                                         \
        float p4 = s4 + rorf<8>(s4);                                         \
        float p5 = s5 + rorf<8>(s5);                                         \
        float p6 = s6 + rorf<8>(s6);                                         \
        float p7 = s7 + rorf<8>(s7);                                         \
        float q0 = p0 + rorf<4>(p4);                                         \
        float q1 = p1 + rorf<4>(p5);                                         \
        float q2 = p2 + rorf<4>(p6);                                         \
        float q3 = p3 + rorf<4>(p7);                                         \
        float acc = (q0 + rorf<1>(q1)) + (rorf<2>(q2) + rorf<3>(q3));        \
        float z  = bx[(J)] + acc;                                            \
        float e2 = __expf(2.f * z);                                          \
        float a  = fmaf(-2.f, __builtin_amdgcn_rcpf(e2 + 1.f), 1.f);         \
        _Float16 ah = (_Float16)a;                                           \
        if (wlane) *(((J) & 1) ? wq1 : wq0) = ah;                            \
        if (FIN) {                                                           \
            afin[myrow] = a;                                                 \
            a_state[b * 256 + myrow] = __builtin_bit_cast(unsigned short, ah);\
        }                                                                    \
        asm volatile("s_waitcnt lgkmcnt(0)" ::: "memory");                   \
        __builtin_amdgcn_s_barrier();                                        \
        asm volatile("" ::: "memory");                                       \
    }

        for (int tb = 0; tb + 8 < T_C; tb += 8) {
            f16x8 xn = *(const f16x8*)(xph + tb + 8);
            RNN_STEP(0, false) RNN_STEP(1, false) RNN_STEP(2, false) RNN_STEP(3, false)
            RNN_STEP(4, false) RNN_STEP(5, false) RNN_STEP(6, false) RNN_STEP(7, false)
#pragma unroll
            for (int j = 0; j < 8; ++j) bx[j] = bias + (float)xn[j];
        }
        RNN_STEP(0, false) RNN_STEP(1, false) RNN_STEP(2, false) RNN_STEP(3, false)
        RNN_STEP(4, false) RNN_STEP(5, false) RNN_STEP(6, false) RNN_STEP(7, true)
#undef RNN_STEP

        // --- Phase 3: out = sigmoid(Wya * a_last + Wyb), last chunk only
        if (is_last) {
            const int o  = tid >> 2;   // 0..127
            const int k4 = tid & 3;    // 4-way K split
            const float4* wp = (const float4*)(Wya + (size_t)o * 256 + k4 * 64);
            const float4* ap = (const float4*)(afin + k4 * 64);
            float s = 0.f;
#pragma unroll
            for (int i = 0; i < 16; ++i) {
                float4 wv4 = wp[i];
                float4 a4  = ap[i];
                s += wv4.x * a4.x + wv4.y * a4.y + wv4.z * a4.z + wv4.w * a4.w;
            }
            s += __shfl_xor(s, 1);
            s += __shfl_xor(s, 2);
            if (k4 == 0)
                out[b * 128 + o] = __builtin_amdgcn_rcpf(1.f + __expf(-(s + Wyb[o])));
        }
    } else {
        // ================= XP path (chunk c_xp, 64 t-rows/block) =========
        if (!do_xp) return;
        _Float16* xp = (c_xp & 1) ? xp1 : xp0;
        const int bxp = blockIdx.x - 64;
        const int wv  = tid >> 6;    // 0..7
        const int l15 = lane & 15;
        const int lk  = lane >> 4;   // 0..3
        const int n0  = wv * 32;

        // B fragments (Wax_w rows = N dim, K contiguous) in registers
        f16x8 bfr[2][8];
#pragma unroll
        for (int nt = 0; nt < 2; ++nt) {
            const float* wrow = Ww + (size_t)(n0 + nt * 16 + l15) * 256;
#pragma unroll
            for (int kt = 0; kt < 8; ++kt) {
                const float4* wp = (const float4*)(wrow + kt * 32 + lk * 8);
                float4 v0 = wp[0], v1 = wp[1];
                f16x8 f;
                f[0] = (_Float16)v0.x; f[1] = (_Float16)v0.y;
                f[2] = (_Float16)v0.z; f[3] = (_Float16)v0.w;
                f[4] = (_Float16)v1.x; f[5] = (_Float16)v1.y;
                f[6] = (_Float16)v1.z; f[7] = (_Float16)v1.w;
                bfr[nt][kt] = f;
            }
        }
        const float bias0 = Wb[n0 + l15];
        const float bias1 = Wb[n0 + 16 + l15];

        // stage A tile (64 rows x 256 K) f32 -> f16 LDS
        {
            const int arow = tid >> 3;           // 0..63
            const int acol = (tid & 7) * 32;     // 0..224
            const int r    = bxp * 64 + arow;
            const int bb   = r >> logT;
            const int tl   = r & (T_C - 1);
            const float4* s4 = (const float4*)(x + ((size_t)(bb * 4096 + c_xp * T_C + tl) << 8) + acol);
            _Float16* d = As + arow * 264 + acol;
#pragma unroll
            for (int q = 0; q < 4; ++q) {
                float4 v0 = s4[2 * q], v1 = s4[2 * q + 1];
                f16x8 p;
                p[0] = (_Float16)v0.x; p[1] = (_Float16)v0.y;
                p[2] = (_Float16)v0.z; p[3] = (_Float16)v0.w;
                p[4] = (_Float16)v1.x; p[5] = (_Float16)v1.y;
                p[6] = (_Float16)v1.z; p[7] = (_Float16)v1.w;
                *(f16x8*)(d + q * 8) = p;
            }
        }
        __syncthreads();

        f32x4 acc[4][2] = {};
#pragma unroll
        for (int kt = 0; kt < 8; ++kt) {
#pragma unroll
            for (int mt = 0; mt < 4; ++mt) {
                f16x8 af = *(const f16x8*)(As + (mt * 16 + l15) * 264 + kt * 32 + lk * 8);
                acc[mt][0] = __builtin_amdgcn_mfma_f32_16x16x32_f16(af, bfr[0][kt], acc[mt][0], 0, 0, 0);
                acc[mt][1] = __builtin_amdgcn_mfma_f32_16x16x32_f16(af, bfr[1][kt], acc[mt][1], 0, 0, 0);
            }
        }

        // store xp3[b][h][t]: 4 t-contiguous halves per 8B store
        const int base = bxp * 64;
#pragma unroll
        for (int mt = 0; mt < 4; ++mt) {
            const int rr  = base + mt * 16 + lk * 4;
            const int bb2 = rr >> logT;
            const int tt  = rr & (T_C - 1);
#pragma unroll
            for (int nt = 0; nt < 2; ++nt) {
                const int   h    = n0 + nt * 16 + l15;
                const float bias = (nt == 0) ? bias0 : bias1;
                f16x4 pk;
#pragma unroll
                for (int r2 = 0; r2 < 4; ++r2) pk[r2] = (_Float16)(acc[mt][nt][r2] + bias);
                *(f16x4*)(xp + ((size_t)(bb2 * 256 + h)) * T_C + tt) = pk;
            }
        }
    }
}

// ---------------------------------------------------------------------------
extern "C" void kernel_launch(void* const* d_in, const int* in_sizes, int n_in,
                              void* d_out, int out_size, void* d_ws, size_t ws_size,
                              hipStream_t stream)
{
    (void)in_sizes; (void)n_in; (void)out_size;
    const float* x    = (const float*)d_in[0];
    const float* Waxw = (const float*)d_in[1];
    const float* Waxb = (const float*)d_in[2];
    const float* Waaw = (const float*)d_in[3];
    const float* Waab = (const float*)d_in[4];
    const float* Wyaw = (const float*)d_in[5];
    const float* Wyab = (const float*)d_in[6];
    float* out = (float*)d_out;

    // chunk size: T_C=1024 (4 chunks) for xp/rnn overlap; shrink to fit ws
    // (needs 2 xp chunk buffers + 32KB state).
    int T_C = 1024, logT = 10;
    while (T_C > 128 && (size_t)2 * 64 * T_C * 256 * 2 + 32768 > ws_size) { T_C >>= 1; --logT; }

    _Float16* xp0 = (_Float16*)d_ws;
    _Float16* xp1 = xp0 + (size_t)64 * T_C * 256;
    unsigned short* a_state = (unsigned short*)(xp1 + (size_t)64 * T_C * 256);

    const int nc  = 4096 / T_C;
    const int nxp = T_C;   // xp blocks per chunk (64 t-rows each)
    for (int i = 0; i <= nc; ++i) {
        // launch i: rnn on chunk i-1 (if any) overlapped with xp on chunk i
        k_fused<<<dim3(64 + nxp), dim3(512), 0, stream>>>(
            x, Waxw, Waxb, Waaw, Waab, Wyaw, Wyab, out, xp0, xp1, a_state,
            i - 1, i, i >= 1 ? 1 : 0, i < nc ? 1 : 0, i == nc ? 1 : 0,
            T_C, logT);
    }
}